// Round 2
// baseline (474.799 us; speedup 1.0000x reference)
//
#include <hip/hip_runtime.h>
#include <math.h>

#define NL 6
#define NB 6
#define NS 7
#define ND 512
#define NH 8
#define HDIM 64
#define NFF 2048
#define NROWS (NB*NS)   // 42

__device__ __forceinline__ float wave_sum(float v) {
    v += __shfl_down(v, 32, 64);
    v += __shfl_down(v, 16, 64);
    v += __shfl_down(v, 8, 64);
    v += __shfl_down(v, 4, 64);
    v += __shfl_down(v, 2, 64);
    v += __shfl_down(v, 1, 64);
    return v;
}

// per-lane partial dot of a 512-length vector: lane handles 8 consecutive floats
__device__ __forceinline__ float dot512(const float* __restrict__ a,
                                        const float* __restrict__ b, int lane) {
    int d0 = lane * 8;
    float4 a1 = *(const float4*)(a + d0);
    float4 a2 = *(const float4*)(a + d0 + 4);
    float4 b1 = *(const float4*)(b + d0);
    float4 b2 = *(const float4*)(b + d0 + 4);
    return a1.x*b1.x + a1.y*b1.y + a1.z*b1.z + a1.w*b1.w
         + a2.x*b2.x + a2.y*b2.y + a2.z*b2.z + a2.w*b2.w;
}

// qkv[row][e] = dot(src[row], iw[e]) + ib[e]; row = b*7+s, e in [0,1536)
__global__ void qkv_kernel(const float* __restrict__ features,
                           const float* __restrict__ role,
                           const float* __restrict__ cur,
                           const float* __restrict__ iw,
                           const float* __restrict__ ib,
                           float* __restrict__ qkv) {
    int gw = (blockIdx.x * blockDim.x + threadIdx.x) >> 6;
    int lane = threadIdx.x & 63;
    if (gw >= NROWS * 1536) return;
    int row = gw / 1536;
    int e = gw - row * 1536;
    int b = row / NS, s = row - b * NS;
    const float* src = (b == 0) ? (cur + s * ND) : (features + row * ND);
    int d0 = lane * 8;
    float4 s1 = *(const float4*)(src + d0);
    float4 s2 = *(const float4*)(src + d0 + 4);
    if (s > 0) {
        const float* rp = role + (b * (NS-1) + (s-1)) * ND + d0;
        float4 r1 = *(const float4*)(rp);
        float4 r2 = *(const float4*)(rp + 4);
        s1.x += r1.x; s1.y += r1.y; s1.z += r1.z; s1.w += r1.w;
        s2.x += r2.x; s2.y += r2.y; s2.z += r2.z; s2.w += r2.w;
    }
    const float* wr = iw + e * ND + d0;
    float4 w1 = *(const float4*)(wr);
    float4 w2 = *(const float4*)(wr + 4);
    float acc = s1.x*w1.x + s1.y*w1.y + s1.z*w1.z + s1.w*w1.w
              + s2.x*w2.x + s2.y*w2.y + s2.z*w2.z + s2.w*w2.w;
    acc = wave_sum(acc);
    if (lane == 0) qkv[row * 1536 + e] = acc + ib[e];
}

// one block (64 threads) per (b,h); full 7x7 attention
__global__ void attn_kernel(const float* __restrict__ qkv, float* __restrict__ ctx) {
    int b = blockIdx.x >> 3, h = blockIdx.x & 7;
    int lane = threadIdx.x;  // 0..63
    __shared__ float q[NS][HDIM], k[NS][HDIM], v[NS][HDIM], att[NS][NS];
    for (int s = 0; s < NS; s++) {
        const float* base = qkv + (size_t)(b*NS + s) * 1536 + h * HDIM + lane;
        q[s][lane] = base[0];
        k[s][lane] = base[ND];
        v[s][lane] = base[2*ND];
    }
    __syncthreads();
    if (lane < NS*NS) {
        int i = lane / NS, j = lane - (lane / NS) * NS;
        float acc = 0.f;
        for (int d = 0; d < HDIM; d++) acc += q[i][d] * k[j][d];
        att[i][j] = acc * 0.125f;
    }
    __syncthreads();
    if (lane < NS) {
        float m = -1e30f;
        for (int j = 0; j < NS; j++) m = fmaxf(m, att[lane][j]);
        float e[NS]; float sum = 0.f;
        for (int j = 0; j < NS; j++) { e[j] = expf(att[lane][j] - m); sum += e[j]; }
        float inv = 1.f / sum;
        for (int j = 0; j < NS; j++) att[lane][j] = e[j] * inv;
    }
    __syncthreads();
    for (int s = 0; s < NS; s++) {
        float acc = 0.f;
        for (int j = 0; j < NS; j++) acc += att[s][j] * v[j][lane];
        ctx[(size_t)(b*NS + s) * ND + h * HDIM + lane] = acc;
    }
}

// msg[row][e] = dot(ctx[row], ow[e]) + ob[e]
__global__ void msg_kernel(const float* __restrict__ ctx,
                           const float* __restrict__ ow,
                           const float* __restrict__ ob,
                           float* __restrict__ msg) {
    int gw = (blockIdx.x * blockDim.x + threadIdx.x) >> 6;
    int lane = threadIdx.x & 63;
    if (gw >= NROWS * ND) return;
    int row = gw / ND, e = gw - row * ND;
    float acc = wave_sum(dot512(ctx + (size_t)row * ND, ow + (size_t)e * ND, lane));
    if (lane == 0) msg[row * ND + e] = acc + ob[e];
}

// aggv[j] = sigmoid(dot(verb_flat(2560), a1_w[j]) + a1_b[j])
// aggn[j] = sigmoid(dot(noun_flat(3072), a2_w[j]) + a2_b[j])
__global__ void agg_kernel(const float* __restrict__ msg,
                           const float* __restrict__ aw1, const float* __restrict__ ab1,
                           const float* __restrict__ aw2, const float* __restrict__ ab2,
                           float* __restrict__ aggv, float* __restrict__ aggn) {
    int gw = (blockIdx.x * blockDim.x + threadIdx.x) >> 6;
    int lane = threadIdx.x & 63;
    if (gw < ND) {
        int j = gw;
        float acc = 0.f;
        // verb_flat chunk c (=batch c+1) is msg[(c+1)*7 + 0][:]
        for (int c = 0; c < 5; c++)
            acc += dot512(msg + (size_t)(c+1)*NS*ND, aw1 + (size_t)j*2560 + c*ND, lane);
        acc = wave_sum(acc);
        if (lane == 0) aggv[j] = 1.f / (1.f + expf(-(acc + ab1[j])));
    } else if (gw < 2*ND) {
        int j = gw - ND;
        float acc = 0.f;
        // noun_flat chunk c (=row c+1 of batch 0) is msg[c+1][:] (contiguous)
        for (int c = 0; c < 6; c++)
            acc += dot512(msg + (size_t)(c+1)*ND, aw2 + (size_t)j*3072 + c*ND, lane);
        acc = wave_sum(acc);
        if (lane == 0) aggn[j] = 1.f / (1.f + expf(-(acc + ab2[j])));
    }
}

// row 0: xln[0] = ln(cur[0]+aggn, l3); rows 1..6: xln[r] = ln(cur[r]+aggv, l1)
__global__ void ln13_kernel(const float* __restrict__ cur,
                            const float* __restrict__ aggv, const float* __restrict__ aggn,
                            const float* __restrict__ l1w, const float* __restrict__ l1b,
                            const float* __restrict__ l3w, const float* __restrict__ l3b,
                            float* __restrict__ xln) {
    int r = blockIdx.x, t = threadIdx.x;
    const float* agg = (r == 0) ? aggn : aggv;
    const float* w   = (r == 0) ? l3w : l1w;
    const float* bb  = (r == 0) ? l3b : l1b;
    float x0 = cur[r*ND + t]       + agg[t];
    float x1 = cur[r*ND + 256 + t] + agg[256 + t];
    __shared__ float sd[4];
    int lane = t & 63, wv = t >> 6;
    float v = wave_sum(x0 + x1);
    if (lane == 0) sd[wv] = v;
    __syncthreads();
    float mu = (sd[0] + sd[1] + sd[2] + sd[3]) * (1.f / ND);
    __syncthreads();
    float d0 = x0 - mu, d1 = x1 - mu;
    v = wave_sum(d0*d0 + d1*d1);
    if (lane == 0) sd[wv] = v;
    __syncthreads();
    float var = (sd[0] + sd[1] + sd[2] + sd[3]) * (1.f / ND);
    float inv = rsqrtf(var + 1e-5f);
    xln[r*ND + t]       = d0 * inv * w[t]     + bb[t];
    xln[r*ND + 256 + t] = d1 * inv * w[256+t] + bb[256+t];
}

// row 0: h[0][f] = relu(dot(xln[0], w21[f]) + b21[f]); rows 1..6 use w11/b11
__global__ void ffa_kernel(const float* __restrict__ xln,
                           const float* __restrict__ w11, const float* __restrict__ b11,
                           const float* __restrict__ w21, const float* __restrict__ b21,
                           float* __restrict__ h) {
    int gw = (blockIdx.x * blockDim.x + threadIdx.x) >> 6;
    int lane = threadIdx.x & 63;
    if (gw >= NS * NFF) return;
    int r = gw / NFF, f = gw - r * NFF;
    const float* W = (r == 0) ? (w21 + (size_t)f * ND) : (w11 + (size_t)f * ND);
    const float* bias = (r == 0) ? b21 : b11;
    float acc = wave_sum(dot512(xln + r * ND, W, lane));
    if (lane == 0) h[r * NFF + f] = fmaxf(acc + bias[f], 0.f);
}

// row 0: ff[0][d] = xln[0][d] + dot(h[0], w22[d]) + b22[d]; rows 1..6 use w12/b12
__global__ void ffb_kernel(const float* __restrict__ xln, const float* __restrict__ hbuf,
                           const float* __restrict__ w12, const float* __restrict__ b12,
                           const float* __restrict__ w22, const float* __restrict__ b22,
                           float* __restrict__ ff) {
    int gw = (blockIdx.x * blockDim.x + threadIdx.x) >> 6;
    int lane = threadIdx.x & 63;
    if (gw >= NS * ND) return;
    int r = gw / ND, d = gw - r * ND;
    const float* W = (r == 0) ? (w22 + (size_t)d * NFF) : (w12 + (size_t)d * NFF);
    const float* bias = (r == 0) ? b22 : b12;
    const float* hin = hbuf + r * NFF;
    float acc = 0.f;
    for (int c = 0; c < 4; c++) acc += dot512(hin + c*ND, W + c*ND, lane);
    acc = wave_sum(acc);
    if (lane == 0) ff[r * ND + d] = xln[r * ND + d] + acc + bias[d];
}

// row 0: cur[0] = ln(ff[0], l4); rows 1..6: cur[r] = ln(ff[r], l2); optionally write out
__global__ void ln24_kernel(const float* __restrict__ ff,
                            const float* __restrict__ l2w, const float* __restrict__ l2b,
                            const float* __restrict__ l4w, const float* __restrict__ l4b,
                            float* __restrict__ cur, float* __restrict__ outp) {
    int r = blockIdx.x, t = threadIdx.x;
    const float* w  = (r == 0) ? l4w : l2w;
    const float* bb = (r == 0) ? l4b : l2b;
    float x0 = ff[r*ND + t], x1 = ff[r*ND + 256 + t];
    __shared__ float sd[4];
    int lane = t & 63, wv = t >> 6;
    float v = wave_sum(x0 + x1);
    if (lane == 0) sd[wv] = v;
    __syncthreads();
    float mu = (sd[0] + sd[1] + sd[2] + sd[3]) * (1.f / ND);
    __syncthreads();
    float d0 = x0 - mu, d1 = x1 - mu;
    v = wave_sum(d0*d0 + d1*d1);
    if (lane == 0) sd[wv] = v;
    __syncthreads();
    float var = (sd[0] + sd[1] + sd[2] + sd[3]) * (1.f / ND);
    float inv = rsqrtf(var + 1e-5f);
    float y0 = d0 * inv * w[t]     + bb[t];
    float y1 = d1 * inv * w[256+t] + bb[256+t];
    cur[r*ND + t]       = y0;
    cur[r*ND + 256 + t] = y1;
    if (outp) {
        outp[r*ND + t]       = y0;
        outp[r*ND + 256 + t] = y1;
    }
}

extern "C" void kernel_launch(void* const* d_in, const int* in_sizes, int n_in,
                              void* d_out, int out_size, void* d_ws, size_t ws_size,
                              hipStream_t stream) {
    const float* features = (const float*)d_in[0];
    const float* role     = (const float*)d_in[1];
    const float* in_w  = (const float*)d_in[2];
    const float* in_b  = (const float*)d_in[3];
    const float* out_w = (const float*)d_in[4];
    const float* out_b = (const float*)d_in[5];
    const float* ln1_w = (const float*)d_in[6];
    const float* ln1_b = (const float*)d_in[7];
    const float* ln2_w = (const float*)d_in[8];
    const float* ln2_b = (const float*)d_in[9];
    const float* ln3_w = (const float*)d_in[10];
    const float* ln3_b = (const float*)d_in[11];
    const float* ln4_w = (const float*)d_in[12];
    const float* ln4_b = (const float*)d_in[13];
    const float* f1_w1 = (const float*)d_in[14];
    const float* f1_b1 = (const float*)d_in[15];
    const float* f1_w2 = (const float*)d_in[16];
    const float* f1_b2 = (const float*)d_in[17];
    const float* f2_w1 = (const float*)d_in[18];
    const float* f2_b1 = (const float*)d_in[19];
    const float* f2_w2 = (const float*)d_in[20];
    const float* f2_b2 = (const float*)d_in[21];
    const float* a1_w  = (const float*)d_in[22];
    const float* a1_b  = (const float*)d_in[23];
    const float* a2_w  = (const float*)d_in[24];
    const float* a2_b  = (const float*)d_in[25];

    float* ws   = (float*)d_ws;
    float* cur  = ws;               // 3584
    float* qkv  = ws + 3584;        // 64512
    float* ctx  = qkv + 64512;      // 21504
    float* msg  = ctx + 21504;      // 21504
    float* aggv = msg + 21504;      // 512
    float* aggn = aggv + 512;       // 512
    float* xln  = aggn + 512;       // 3584
    float* hbuf = xln + 3584;       // 14336
    float* ff   = hbuf + 14336;     // 3584

    hipMemcpyAsync(cur, features, 3584 * sizeof(float), hipMemcpyDeviceToDevice, stream);

    for (int l = 0; l < NL; l++) {
        qkv_kernel<<<NROWS*1536/4, 256, 0, stream>>>(
            features, role, cur, in_w + (size_t)l*1536*ND, in_b + (size_t)l*1536, qkv);
        attn_kernel<<<NB*NH, 64, 0, stream>>>(qkv, ctx);
        msg_kernel<<<NROWS*ND/4, 256, 0, stream>>>(
            ctx, out_w + (size_t)l*ND*ND, out_b + (size_t)l*ND, msg);
        agg_kernel<<<2*ND/4, 256, 0, stream>>>(
            msg, a1_w + (size_t)l*ND*2560, a1_b + (size_t)l*ND,
                 a2_w + (size_t)l*ND*3072, a2_b + (size_t)l*ND, aggv, aggn);
        ln13_kernel<<<NS, 256, 0, stream>>>(
            cur, aggv, aggn, ln1_w + (size_t)l*ND, ln1_b + (size_t)l*ND,
            ln3_w + (size_t)l*ND, ln3_b + (size_t)l*ND, xln);
        ffa_kernel<<<NS*NFF/4, 256, 0, stream>>>(
            xln, f1_w1 + (size_t)l*NFF*ND, f1_b1 + (size_t)l*NFF,
                 f2_w1 + (size_t)l*NFF*ND, f2_b1 + (size_t)l*NFF, hbuf);
        ffb_kernel<<<NS*ND/4, 256, 0, stream>>>(
            xln, hbuf, f1_w2 + (size_t)l*ND*NFF, f1_b2 + (size_t)l*ND,
                       f2_w2 + (size_t)l*ND*NFF, f2_b2 + (size_t)l*ND, ff);
        ln24_kernel<<<NS, 256, 0, stream>>>(
            ff, ln2_w + (size_t)l*ND, ln2_b + (size_t)l*ND,
                ln4_w + (size_t)l*ND, ln4_b + (size_t)l*ND,
            cur, (l == NL-1) ? (float*)d_out : nullptr);
    }
}